// Round 9
// baseline (216.573 us; speedup 1.0000x reference)
//
#include <hip/hip_runtime.h>
#include <hip/hip_bf16.h>

typedef _Float16 half2v __attribute__((ext_vector_type(2)));
typedef _Float16 half8  __attribute__((ext_vector_type(8)));
typedef __fp16   fp16x2 __attribute__((ext_vector_type(2)));
typedef float f32x4 __attribute__((ext_vector_type(4)));

union FragF16 { half8 v; half2v h[4]; };
union Cvt2 { fp16x2 f; half2v h; };

// Block = 4 waves over 32 b's: wave w -> d = w&1, b-group = w>>1 (16 b's each).
// R8 analysis: latency-bound (~25% true issue util); the per-c-iter serial
// chain ended in 2 ds_swizzle reduces + exp. This version DEFERS the
// cross-quad reduction: per c-iter each lane writes its quad-partial p to LDS
// (fire-and-forget ds_write_b32, lane-constant address + immediate), so
// c-iters overlap. Per b: one readback (8 ds_read_b32, 2-way banks = free,
// double-buffered by b parity), 2 exps/lane, one 6-shuffle wave reduce.
// z/u prefetched one b ahead (R7: removing prefetch cost ~60 us).
//
// NOTE: no 2nd __launch_bounds__ arg — (256,4) forced a 64-VGPR budget and
// spilled all persistent fragments to scratch (1.9 GB FETCH, 657 us; R5).
__global__ __launch_bounds__(256) void monotone_nn_kernel(
    const float* __restrict__ zin, const float* __restrict__ uin,
    const float* __restrict__ w01, const float* __restrict__ b01,
    const float* __restrict__ w02, const float* __restrict__ b02,
    const float* __restrict__ w03, const float* __restrict__ b03,
    const float* __restrict__ w11, const float* __restrict__ b11,
    const float* __restrict__ w12, const float* __restrict__ b12,
    const float* __restrict__ w13, const float* __restrict__ b13,
    const float* __restrict__ biasp, const int* __restrict__ lbp,
    float* __restrict__ out)
{
    __shared__ float lds_hz[4][16];
    __shared__ float lds_v[2][64];
    // per wave, 2 parity buffers, 4 quads x 136-stride points (stride 136 ->
    // quad bases 8 banks apart -> 2-way conflicts max on write AND read)
    __shared__ float lds_p[4][2][4 * 136];

    const int tid  = threadIdx.x;
    const int lane = tid & 63;
    const int wave = tid >> 6;
    const int lrow = lane & 15;   // MFMA col index (grid point) / A-row within tile
    const int quad = lane >> 4;

    const int d  = wave & 1;
    const int bg = wave >> 1;
    const int b0 = blockIdx.x * 32 + bg * 16;   // 16 b's per wave

    const float lb    = (float)lbp[0];
    const float biasv = biasp[0];

    const float* w1p = d ? w11 : w01;
    const float* b1p = d ? b11 : b01;
    const float* w2p = d ? w12 : w02;
    const float* b2p = d ? b12 : b02;
    const float* w3p = d ? w13 : w03;
    const float  b3  = (d ? b13 : b03)[0];

    // --- cooperative vfold = 0.505 * (w3^T W2): one column per lane, coalesced ---
    if (bg == 0) {
        float va = 0.0f;
        #pragma unroll 8
        for (int f = 0; f < 64; ++f)
            va = fmaf(w3p[f], w2p[f * 64 + lane], va);
        lds_v[d][lane] = 0.505f * va;
    }

    // --- preload per-lane weight slices ---
    // layer-1 packed fp16: lane computes h1[h] for h = kc*32 + quad*8 + j
    half2v w1pk[8], b1pk[8];
    #pragma unroll
    for (int kc = 0; kc < 2; ++kc)
        #pragma unroll
        for (int jj = 0; jj < 4; ++jj) {
            const int h = kc * 32 + quad * 8 + 2 * jj;
            half2v w, bb;
            w[0]  = (_Float16)w1p[h];     w[1]  = (_Float16)w1p[h + 1];
            bb[0] = (_Float16)b1p[h];     bb[1] = (_Float16)b1p[h + 1];
            w1pk[kc * 4 + jj] = w;
            b1pk[kc * 4 + jj] = bb;
        }

    // epilogue: lane holds h2 features f = t*16 + quad*4 + r
    // w3 (x0.495) as fp16 pairs; b2 as f32 C-operand init
    half2v w3pk[8];
    f32x4 b2v[4];
    float bd = 0.0f;
    #pragma unroll
    for (int t = 0; t < 4; ++t) {
        #pragma unroll
        for (int r = 0; r < 4; ++r) {
            const int f = t * 16 + quad * 4 + r;
            b2v[t][r] = b2p[f];
            bd = fmaf(w3p[f], b2p[f], bd);
        }
        #pragma unroll
        for (int rr = 0; rr < 2; ++rr) {
            const int f = t * 16 + quad * 4 + 2 * rr;
            half2v w;
            w[0] = (_Float16)(0.495f * w3p[f]);
            w[1] = (_Float16)(0.495f * w3p[f + 1]);
            w3pk[t * 2 + rr] = w;
        }
    }
    // b3' = b3 + 0.505*(w3.b2)
    bd += __shfl_xor(bd, 16);
    bd += __shfl_xor(bd, 32);
    const float b3p_ = b3 + 0.505f * bd;

    // A-frags (fp16): A[f][h] = w2[f][h]; frag (t,kc): w2[t*16+lrow][kc*32+quad*8+j]
    FragF16 afrag[8];
    #pragma unroll
    for (int t = 0; t < 4; ++t)
        #pragma unroll
        for (int kc = 0; kc < 2; ++kc) {
            const float* src = w2p + (t * 16 + lrow) * 64 + kc * 32 + quad * 8;
            #pragma unroll
            for (int j = 0; j < 8; ++j)
                afrag[t * 2 + kc].v[j] = (_Float16)src[j];
        }

    __syncthreads();

    // vfold pairs as fp16, matching bfrag pair layout (k = kc*32+quad*8+2jj)
    half2v vpk[8];
    #pragma unroll
    for (int kc = 0; kc < 2; ++kc)
        #pragma unroll
        for (int jj = 0; jj < 4; ++jj) {
            const float2 vv = *(const float2*)&lds_v[d][kc * 32 + quad * 8 + 2 * jj];
            half2v t;
            t[0] = (_Float16)vv.x;
            t[1] = (_Float16)vv.y;
            vpk[kc * 4 + jj] = t;
        }

    const float lrowf = (float)lrow;
    const half2v k001 = { (_Float16)0.01f, (_Float16)0.01f };

    const int wslot = 136 * quad + lrow;   // write index (loop-invariant)

    // --- prefetch b0 (z and u) ---
    float zv_nxt = zin[b0 * 2 + d];
    float u_nxt[8];
    {
        const float* ubn = uin + (size_t)(b0 * 2 + d) * 127;
        #pragma unroll
        for (int c = 0; c < 8; ++c) {
            const int idx = c * 16 + lrow;
            const bool ok = (c < 7) || (lrow < 15);
            u_nxt[c] = ok ? ubn[idx] : 0.0f;
        }
    }

    #pragma unroll 1
    for (int i = 0; i < 16; ++i) {
        const float zv = zv_nxt;
        float uu[8];
        #pragma unroll
        for (int c = 0; c < 8; ++c) uu[c] = u_nxt[c];

        // prefetch next b
        const int bn = b0 + ((i < 15) ? i + 1 : 15);
        zv_nxt = zin[bn * 2 + d];
        {
            const float* ubn = uin + (size_t)(bn * 2 + d) * 127;
            #pragma unroll
            for (int c = 0; c < 8; ++c) {
                const int idx = c * 16 + lrow;
                const bool ok = (c < 7) || (lrow < 15);
                u_nxt[c] = ok ? ubn[idx] : 0.0f;
            }
        }

        const float ds = (fmaxf(zv, lb) - lb) * (1.0f / 127.0f);
        float* wp = &lds_p[wave][i & 1][0];

        #pragma unroll
        for (int c = 0; c < 8; ++c) {
            const float x = fmaf(ds, lrowf + (float)(c * 16) + uu[c], lb);

            const _Float16 xh = (_Float16)x;
            const half2v x2 = { xh, xh };

            // B-frag: h1 = pk_max(t, 0.01*t)
            FragF16 bfrag[2];
            #pragma unroll
            for (int kc = 0; kc < 2; ++kc)
                #pragma unroll
                for (int jj = 0; jj < 4; ++jj) {
                    const half2v t0 = x2 * w1pk[kc * 4 + jj] + b1pk[kc * 4 + jj];
                    bfrag[kc].h[jj] = __builtin_elementwise_max(t0, t0 * k001);
                }

            // p1 = vfold . h1 (v_dot2_f32_f16)
            float p1 = 0.0f;
            #pragma unroll
            for (int kc = 0; kc < 2; ++kc)
                #pragma unroll
                for (int jj = 0; jj < 4; ++jj)
                    p1 = __builtin_amdgcn_fdot2(bfrag[kc].h[jj], vpk[kc * 4 + jj], p1, false);

            // p2 = (0.495*w3) . |h2|
            float p2 = 0.0f;
            #pragma unroll
            for (int t = 0; t < 4; ++t) {
                f32x4 dacc;
                dacc = __builtin_amdgcn_mfma_f32_16x16x32_f16(afrag[t * 2 + 0].v, bfrag[0].v, b2v[t], 0, 0, 0);
                dacc = __builtin_amdgcn_mfma_f32_16x16x32_f16(afrag[t * 2 + 1].v, bfrag[1].v, dacc,   0, 0, 0);
                #pragma unroll
                for (int rr = 0; rr < 2; ++rr) {
                    Cvt2 cv;
                    cv.f = __builtin_amdgcn_cvt_pkrtz(fabsf(dacc[2 * rr]), fabsf(dacc[2 * rr + 1]));
                    p2 = __builtin_amdgcn_fdot2(cv.h, w3pk[t * 2 + rr], p2, false);
                }
            }

            // fire-and-forget: quad-partial for point c*16+lrow
            wp[wslot + c * 16] = p1 + p2;
        }

        // --- per-b readback: each lane owns points (lane, lane+64) ---
        const float* rp = &lds_p[wave][i & 1][0];
        const float a00 = rp[lane +   0] + rp[lane + 136];
        const float a01 = rp[lane + 272] + rp[lane + 408];
        const float a10 = rp[lane +  64] + rp[lane + 200];
        const float a11 = rp[lane + 336] + rp[lane + 472];
        const float s0 = a00 + a01 + b3p_;
        const float s1 = a10 + a11 + b3p_;
        const float e0 = __builtin_amdgcn_exp2f(s0 * 1.4426950408889634f);
        const float e1 = __builtin_amdgcn_exp2f(s1 * 1.4426950408889634f);
        float acc = ((s0 > 0.0f) ? (s0 + 1.0f) : e0)
                  + ((s1 > 0.0f) ? (s1 + 1.0f) : e1);

        // wave-wide reduce (64 lanes)
        acc += __shfl_xor(acc, 1);
        acc += __shfl_xor(acc, 2);
        acc += __shfl_xor(acc, 4);
        acc += __shfl_xor(acc, 8);
        acc += __shfl_xor(acc, 16);
        acc += __shfl_xor(acc, 32);

        if (lane == 0) lds_hz[wave][i] = acc * ds;
    }

    __syncthreads();
    if (tid < 32) {
        const int g = tid >> 4, l = tid & 15;
        out[blockIdx.x * 32 + g * 16 + l] = lds_hz[2 * g][l] + lds_hz[2 * g + 1][l] + biasv;
    }
}

extern "C" void kernel_launch(void* const* d_in, const int* in_sizes, int n_in,
                              void* d_out, int out_size, void* d_ws, size_t ws_size,
                              hipStream_t stream) {
    const float* z    = (const float*)d_in[0];
    const float* u    = (const float*)d_in[1];
    const float* w0_1 = (const float*)d_in[2];
    const float* b0_1 = (const float*)d_in[3];
    const float* w0_2 = (const float*)d_in[4];
    const float* b0_2 = (const float*)d_in[5];
    const float* w0_3 = (const float*)d_in[6];
    const float* b0_3 = (const float*)d_in[7];
    const float* w1_1 = (const float*)d_in[8];
    const float* b1_1 = (const float*)d_in[9];
    const float* w1_2 = (const float*)d_in[10];
    const float* b1_2 = (const float*)d_in[11];
    const float* w1_3 = (const float*)d_in[12];
    const float* b1_3 = (const float*)d_in[13];
    const float* bias = (const float*)d_in[14];
    const int*   lbp  = (const int*)d_in[16];

    // 32768 b * 2 d; each block covers 32 b's (4 waves: 2 b-groups x 2 d)
    monotone_nn_kernel<<<dim3(1024), dim3(256), 0, stream>>>(
        z, u, w0_1, b0_1, w0_2, b0_2, w0_3, b0_3,
        w1_1, b1_1, w1_2, b1_2, w1_3, b1_3,
        bias, lbp, (float*)d_out);
}